// Round 5
// baseline (994.065 us; speedup 1.0000x reference)
//
#include <hip/hip_runtime.h>
#include <math.h>

#define N0c   16
#define NAt   96
#define ORIG  92
#define Fc    64
#define Kc    41
#define Hc    128
#define NCc   3
#define C2    128   // 2F
#define EPSBN 1e-5f
#define JG    4     // j-groups per block
#define JPW   (NAt / JG)   // 24 j's per group

__device__ __forceinline__ float sp_(float x){
    // stable softplus: max(x,0) + log1p(exp(-|x|))
    return fmaxf(x, 0.f) + log1pf(expf(-fabsf(x)));
}
__device__ __forceinline__ float sgm_(float x){
    return 1.f / (1.f + expf(-x));
}

// fea = atom @ emb_W + emb_b   (1536 x 92) @ (92 x 64)
__global__ __launch_bounds__(256) void k_embed(const float* __restrict__ atom,
                                               const float* __restrict__ W,
                                               const float* __restrict__ b,
                                               float* __restrict__ fea){
    int row = blockIdx.x * 4 + (threadIdx.x >> 6);   // wave-uniform row
    int f   = threadIdx.x & 63;
    const float* ar = atom + row * ORIG;
    float acc = b[f];
    #pragma unroll 4
    for (int o = 0; o < ORIG; ++o) acc += ar[o] * W[o * Fc + f];
    fea[row * Fc + f] = acc;
}

// One-time: S_r[k]=sum_j nbr, T_r[k]=sum_j adj*nbr, cnt_r=sum_j adj.
// Layer-invariant (depends only on inputs). block=256 (4 waves x 24 j's).
__global__ __launch_bounds__(256) void k_pre(const float* __restrict__ nbr,
                                             const int*   __restrict__ adj,
                                             float* __restrict__ ST,
                                             float* __restrict__ cntf){
    int r    = blockIdx.x;
    int lane = threadIdx.x & 63;
    int jg   = __builtin_amdgcn_readfirstlane(threadIdx.x >> 6);
    __shared__ float rS[JG][Kc], rT[JG][Kc], rc[JG];
    float S = 0.f, T = 0.f, cn = 0.f;
    int j0 = jg * JPW;
    for (int j = j0; j < j0 + JPW; ++j){
        float a = (float)adj[r * NAt + j];           // uniform s_load
        float v = (lane < Kc) ? nbr[((size_t)r * NAt + j) * Kc + lane] : 0.f;
        S += v; T += a * v; cn += a;
    }
    if (lane < Kc){ rS[jg][lane] = S; rT[jg][lane] = T; }
    if (lane == 0) rc[jg] = cn;
    __syncthreads();
    int t = threadIdx.x;
    if (t < Kc){
        ST[r * (2 * Kc) + t]      = rS[0][t] + rS[1][t] + rS[2][t] + rS[3][t];
        ST[r * (2 * Kc) + Kc + t] = rT[0][t] + rT[1][t] + rT[2][t] + rT[3][t];
    }
    if (t == 0) cntf[r] = rc[0] + rc[1] + rc[2] + rc[3];
}

// One-time: G[k][l] = sum_{r,j} nbr[r,j,k]*nbr[r,j,l]  (41x41, atomic-accum).
// Stage the (96x41) row block in LDS; thread owns k = t%41 and 7 l's.
__global__ __launch_bounds__(256) void k_gram(const float* __restrict__ nbr,
                                              float* __restrict__ G){
    int r = blockIdx.x;
    __shared__ float L[NAt * Kc];                    // 3936 floats = 15.7 KB
    for (int idx = threadIdx.x; idx < NAt * Kc; idx += 256)
        L[idx] = nbr[(size_t)r * NAt * Kc + idx];
    __syncthreads();
    int t = threadIdx.x;
    if (t < 246){
        int k  = t % Kc;
        int lb = (t / Kc) * 7;                       // 6 groups x 7 covers 41
        float acc[7] = {0,0,0,0,0,0,0};
        #pragma unroll 2
        for (int j = 0; j < NAt; ++j){
            float vk = L[j * Kc + k];
            #pragma unroll
            for (int m = 0; m < 7; ++m){
                int l = lb + m;
                if (l < Kc) acc[m] += vk * L[j * Kc + l];
            }
        }
        #pragma unroll
        for (int m = 0; m < 7; ++m){
            int l = lb + m;
            if (l < Kc) atomicAdd(&G[k * Kc + l], acc[m]);
        }
    }
}

// p1[r,c] = fea[r,:]·W[0:64,c] + conv_b[c] ; p2[r,c] = fea[r,:]·W[64:128,c]
__global__ __launch_bounds__(128) void k_p12(const float* __restrict__ fea,
                                             const float* __restrict__ Wl,
                                             const float* __restrict__ bl,
                                             float* __restrict__ p1,
                                             float* __restrict__ p2){
    int bi = blockIdx.x;
    int c  = threadIdx.x;
    const float* fr = fea + bi * Fc;
    float a1 = bl[c], a2 = 0.f;
    #pragma unroll 4
    for (int f = 0; f < Fc; ++f){
        float fv = fr[f];                 // uniform -> scalar load
        a1 += fv * Wl[f * C2 + c];
        a2 += fv * Wl[(Fc + f) * C2 + c];
    }
    p1[bi * C2 + c] = a1;
    p2[bi * C2 + c] = a2;
}

// BN1 stats from closed form (per-r part). 4 r's per block, c = thread.
// sum1 += 96*p1 + cnt*p2 + S_r·w3 ; sq1 += 96p1^2 + cnt p2^2 + 2cnt p1p2
//         + 2p1(S_r·w3) + 2p2(T_r·w3).  (G-term added in k_fin1.)
__global__ __launch_bounds__(128) void k_stats2(const float* __restrict__ ST,
                                                const float* __restrict__ cntf,
                                                const float* __restrict__ Wl,
                                                const float* __restrict__ p1,
                                                const float* __restrict__ p2,
                                                float* __restrict__ sum1,
                                                float* __restrict__ sq1){
    int c  = threadIdx.x;
    int r0 = blockIdx.x * 4;
    float w3[Kc];
    #pragma unroll
    for (int k = 0; k < Kc; ++k) w3[k] = Wl[(C2 + k) * C2 + c];
    float s1 = 0.f, q1 = 0.f;
    for (int rr = 0; rr < 4; ++rr){
        int r = r0 + rr;
        const float* Sr = ST + r * (2 * Kc);         // uniform -> s_loads
        const float* Tr = Sr + Kc;
        float p1v = p1[r * C2 + c], p2v = p2[r * C2 + c];
        float u = 0.f, t = 0.f;
        #pragma unroll
        for (int k = 0; k < Kc; ++k){
            u += Sr[k] * w3[k];
            t += Tr[k] * w3[k];
        }
        float cn = cntf[r];                          // uniform
        s1 += (float)NAt * p1v + cn * p2v + u;
        q1 += (float)NAt * p1v * p1v + cn * p2v * p2v
            + 2.f * cn * p1v * p2v + 2.f * p1v * u + 2.f * p2v * t;
    }
    atomicAdd(&sum1[c], s1);
    atomicAdd(&sq1[c],  q1);
}

// BN1 finalize: add global Gram term q = w3^T G w3 to sq, then affine fold.
__global__ void k_fin1(const float* __restrict__ sum, const float* __restrict__ sq,
                       const float* __restrict__ G,   const float* __restrict__ Wl,
                       const float* __restrict__ g,   const float* __restrict__ b,
                       float* __restrict__ a, float* __restrict__ bb, float invM){
    int c = threadIdx.x;
    float w3[Kc];
    #pragma unroll
    for (int k = 0; k < Kc; ++k) w3[k] = Wl[(C2 + k) * C2 + c];
    float q = 0.f;
    for (int k = 0; k < Kc; ++k){
        const float* Gr = G + k * Kc;                // uniform -> s_loads
        float gw = 0.f;
        #pragma unroll
        for (int l = 0; l < Kc; ++l) gw += Gr[l] * w3[l];
        q += w3[k] * gw;
    }
    float m = sum[c] * invM;
    float v = (sq[c] + q) * invM - m * m;
    float ac = g[c] * rsqrtf(v + EPSBN);
    a[c]  = ac;
    bb[c] = b[c] - m * ac;
}

// BN2 finalize (plain).
__global__ void k_fin(const float* __restrict__ sum, const float* __restrict__ sq,
                      const float* __restrict__ g,   const float* __restrict__ b,
                      float* __restrict__ a, float* __restrict__ bb, float invM){
    int c = threadIdx.x;
    float m = sum[c] * invM;
    float v = sq[c] * invM - m * m;
    float ac = g[c] * rsqrtf(v + EPSBN);
    a[c]  = ac;
    bb[c] = b[c] - m * ac;
}

// Pass 2: recompute gated, BN1, sigmoid*softplus, sum over j; BN2 stats.
// R3 structure; only change: launch_bounds min-waves 2 -> 1 so the allocator
// may keep wa/wb (82 floats) in arch VGPRs instead of AGPR-offloading.
__global__ __launch_bounds__(256, 1) void k_apply(const float* __restrict__ nbr,
                                                  const int*   __restrict__ adj,
                                                  const float* __restrict__ Wl,
                                                  const float* __restrict__ p1,
                                                  const float* __restrict__ p2,
                                                  const float* __restrict__ a1,
                                                  const float* __restrict__ bb1,
                                                  float* __restrict__ summed,
                                                  float* __restrict__ sum2,
                                                  float* __restrict__ sq2){
    int bi = blockIdx.x;
    int f  = threadIdx.x & 63;
    int jg = __builtin_amdgcn_readfirstlane(threadIdx.x >> 6);  // SGPR
    __shared__ float red[JG][Fc];

    float wa[Kc], wb[Kc];                     // register-resident W3 columns
    #pragma unroll
    for (int k = 0; k < Kc; ++k){
        wa[k] = Wl[(C2 + k) * C2 + f];
        wb[k] = Wl[(C2 + k) * C2 + Fc + f];
    }
    float pa1 = p1[bi * C2 + f],      pa2 = p2[bi * C2 + f];
    float pb1 = p1[bi * C2 + Fc + f], pb2 = p2[bi * C2 + Fc + f];
    float A1 = a1[f],      B1 = bb1[f];
    float A2 = a1[Fc + f], B2 = bb1[Fc + f];
    const float* nb = nbr + (size_t)bi * (NAt * Kc);
    const int*   aj = adj + bi * NAt;

    float acc = 0.f;
    int j0 = jg * JPW;
    for (int j = j0; j < j0 + JPW; ++j){
        const float* nr = nb + j * Kc;        // wave-uniform -> s_loads
        float ajf = (float)aj[j];
        float f0 = 0.f, f1 = 0.f, c0 = 0.f, c1 = 0.f;
        #pragma unroll
        for (int k = 0; k < 40; k += 2){
            float n0 = nr[k], n1 = nr[k + 1];
            f0 += n0 * wa[k];     f1 += n1 * wa[k + 1];
            c0 += n0 * wb[k];     c1 += n1 * wb[k + 1];
        }
        { float n0 = nr[40]; f0 += n0 * wa[40]; c0 += n0 * wb[40]; }
        float gf = (pa1 + ajf * pa2 + (f0 + f1)) * A1 + B1;
        float gc = (pb1 + ajf * pb2 + (c0 + c1)) * A2 + B2;
        acc += sgm_(gf) * sp_(gc);
    }
    red[jg][f] = acc;
    __syncthreads();
    if (jg == 0){
        acc = red[0][f] + red[1][f] + red[2][f] + red[3][f];
        summed[bi * Fc + f] = acc;
        atomicAdd(&sum2[f], acc);
        atomicAdd(&sq2[f],  acc * acc);
    }
}

// fea = softplus(fea + BN2(summed))
__global__ __launch_bounds__(256) void k_update(float* __restrict__ fea,
                                                const float* __restrict__ summed,
                                                const float* __restrict__ a2,
                                                const float* __restrict__ bb2){
    int idx = blockIdx.x * 256 + threadIdx.x;
    int f   = idx & 63;
    float v = fea[idx] + summed[idx] * a2[f] + bb2[f];
    fea[idx] = sp_(v);
}

// crys = mean_i fea; out = softplus(softplus(crys)@fcW + fcb) @ outW + outb
__global__ __launch_bounds__(128) void k_final(const float* __restrict__ fea,
                                               const float* __restrict__ fcW,
                                               const float* __restrict__ fcb,
                                               const float* __restrict__ outW,
                                               const float* __restrict__ outb,
                                               float* __restrict__ out){
    int b = blockIdx.x;
    int t = threadIdx.x;
    __shared__ float spc[Fc];
    __shared__ float red[Hc];
    if (t < Fc){
        float s = 0.f;
        for (int i = 0; i < NAt; ++i) s += fea[(b * NAt + i) * Fc + t];
        spc[t] = sp_(s * (1.f / NAt));
    }
    __syncthreads();
    float h = fcb[t];
    #pragma unroll 4
    for (int f = 0; f < Fc; ++f) h += spc[f] * fcW[f * Hc + t];
    h = sp_(h);
    red[t] = h * outW[t];
    __syncthreads();
    for (int off = 64; off > 0; off >>= 1){
        if (t < off) red[t] += red[t + off];
        __syncthreads();
    }
    if (t == 0) out[b] = red[0] + outb[0];
}

extern "C" void kernel_launch(void* const* d_in, const int* in_sizes, int n_in,
                              void* d_out, int out_size, void* d_ws, size_t ws_size,
                              hipStream_t stream){
    const float* atom  = (const float*)d_in[0];
    const float* nbr   = (const float*)d_in[1];
    const int*   adj   = (const int*)  d_in[2];
    const float* embW  = (const float*)d_in[3];
    const float* embB  = (const float*)d_in[4];
    const float* convW = (const float*)d_in[5];
    const float* convB = (const float*)d_in[6];
    const float* bn1g  = (const float*)d_in[7];
    const float* bn1b  = (const float*)d_in[8];
    const float* bn2g  = (const float*)d_in[9];
    const float* bn2b  = (const float*)d_in[10];
    const float* fcW   = (const float*)d_in[11];
    const float* fcb   = (const float*)d_in[12];
    const float* outW  = (const float*)d_in[13];
    const float* outb  = (const float*)d_in[14];
    float* out = (float*)d_out;
    float* ws  = (float*)d_ws;

    const int ROWS = N0c * NAt;            // 1536
    float* fea    = ws;                    // 98304 floats
    float* p1     = ws + 98304;            // 196608
    float* p2     = ws + 294912;           // 196608
    float* summed = ws + 491520;           // 98304
    float* S      = ws + 589824;           // stats block (768)
    float* sum1 = S,       *sq1 = S + 128;
    float* sum2 = S + 256, *sq2 = S + 320;
    float* a1   = S + 384, *bb1 = S + 512;
    float* a2   = S + 640, *bb2 = S + 704;
    float* ST   = ws + 590592;             // 1536*82
    float* cntf = ws + 716544;             // 1536
    float* G    = ws + 718080;             // 41*41 = 1681

    k_embed<<<ROWS / 4, 256, 0, stream>>>(atom, embW, embB, fea);
    k_pre  <<<ROWS, 256, 0, stream>>>(nbr, adj, ST, cntf);
    hipMemsetAsync(G, 0, Kc * Kc * sizeof(float), stream);
    k_gram <<<ROWS, 256, 0, stream>>>(nbr, G);

    for (int l = 0; l < NCc; ++l){
        const float* Wl = convW + (size_t)l * 169 * C2;
        const float* bl = convB + l * C2;
        hipMemsetAsync(S, 0, 384 * sizeof(float), stream);   // sum1,sq1,sum2,sq2
        k_p12   <<<ROWS, C2, 0, stream>>>(fea, Wl, bl, p1, p2);
        k_stats2<<<ROWS / 4, C2, 0, stream>>>(ST, cntf, Wl, p1, p2, sum1, sq1);
        k_fin1  <<<1, C2, 0, stream>>>(sum1, sq1, G, Wl,
                                       bn1g + l * C2, bn1b + l * C2,
                                       a1, bb1, 1.f / (float)(N0c * NAt * NAt));
        k_apply <<<ROWS, 256, 0, stream>>>(nbr, adj, Wl, p1, p2, a1, bb1,
                                           summed, sum2, sq2);
        k_fin   <<<1, Fc, 0, stream>>>(sum2, sq2, bn2g + l * Fc, bn2b + l * Fc,
                                       a2, bb2, 1.f / (float)(N0c * NAt));
        k_update<<<ROWS * Fc / 256, 256, 0, stream>>>(fea, summed, a2, bb2);
    }

    k_final<<<N0c, Hc, 0, stream>>>(fea, fcW, fcb, outW, outb, out);
}

// Round 6
// 542.187 us; speedup vs baseline: 1.8334x; 1.8334x over previous
//
#include <hip/hip_runtime.h>
#include <math.h>

#define N0c   16
#define NAt   96
#define ORIG  92
#define Fc    64
#define Kc    41
#define Hc    128
#define NCc   3
#define C2    128   // 2F
#define EPSBN 1e-5f
#define JG    4     // j-groups per block
#define JPW   (NAt / JG)   // 24 j's per group
#define GBLK  192   // gram partial blocks (8 r's each)
#define RPB   8     // 1536 / 192

__device__ __forceinline__ float sp_(float x){
    // stable softplus: max(x,0) + log1p(exp(-|x|))
    return fmaxf(x, 0.f) + log1pf(expf(-fabsf(x)));
}
__device__ __forceinline__ float sgm_(float x){
    return 1.f / (1.f + expf(-x));
}

// fea = atom @ emb_W + emb_b   (1536 x 92) @ (92 x 64)
__global__ __launch_bounds__(256) void k_embed(const float* __restrict__ atom,
                                               const float* __restrict__ W,
                                               const float* __restrict__ b,
                                               float* __restrict__ fea){
    int row = blockIdx.x * 4 + (threadIdx.x >> 6);   // wave-uniform row
    int f   = threadIdx.x & 63;
    const float* ar = atom + row * ORIG;
    float acc = b[f];
    #pragma unroll 4
    for (int o = 0; o < ORIG; ++o) acc += ar[o] * W[o * Fc + f];
    fea[row * Fc + f] = acc;
}

// One-time: S_r[k]=sum_j nbr, T_r[k]=sum_j adj*nbr, cnt_r=sum_j adj.
__global__ __launch_bounds__(256) void k_pre(const float* __restrict__ nbr,
                                             const int*   __restrict__ adj,
                                             float* __restrict__ ST,
                                             float* __restrict__ cntf){
    int r    = blockIdx.x;
    int lane = threadIdx.x & 63;
    int jg   = __builtin_amdgcn_readfirstlane(threadIdx.x >> 6);
    __shared__ float rS[JG][Kc], rT[JG][Kc], rc[JG];
    float S = 0.f, T = 0.f, cn = 0.f;
    int j0 = jg * JPW;
    for (int j = j0; j < j0 + JPW; ++j){
        float a = (float)adj[r * NAt + j];           // uniform s_load
        float v = (lane < Kc) ? nbr[((size_t)r * NAt + j) * Kc + lane] : 0.f;
        S += v; T += a * v; cn += a;
    }
    if (lane < Kc){ rS[jg][lane] = S; rT[jg][lane] = T; }
    if (lane == 0) rc[jg] = cn;
    __syncthreads();
    int t = threadIdx.x;
    if (t < Kc){
        ST[r * (2 * Kc) + t]      = rS[0][t] + rS[1][t] + rS[2][t] + rS[3][t];
        ST[r * (2 * Kc) + Kc + t] = rT[0][t] + rT[1][t] + rT[2][t] + rT[3][t];
    }
    if (t == 0) cntf[r] = rc[0] + rc[1] + rc[2] + rc[3];
}

// One-time: per-block PRIVATE partial Gram over RPB r-tiles (no atomics),
// written to pG[blk][1681]. Thread owns k = t%41 and 7 l's (t < 246).
__global__ __launch_bounds__(256) void k_gram(const float* __restrict__ nbr,
                                              float* __restrict__ pG){
    int blk = blockIdx.x;
    int t   = threadIdx.x;
    __shared__ float L[NAt * Kc];                    // 15.7 KB
    int k  = t % Kc;
    int lb = (t / Kc) * 7;
    float acc[7] = {0,0,0,0,0,0,0};
    for (int rr = 0; rr < RPB; ++rr){
        int r = blk * RPB + rr;
        __syncthreads();                             // protect L reuse
        for (int idx = t; idx < NAt * Kc; idx += 256)
            L[idx] = nbr[(size_t)r * NAt * Kc + idx];
        __syncthreads();
        if (t < 246){
            #pragma unroll 2
            for (int j = 0; j < NAt; ++j){
                float vk = L[j * Kc + k];
                #pragma unroll
                for (int m = 0; m < 7; ++m){
                    int l = lb + m;
                    if (l < Kc) acc[m] += vk * L[j * Kc + l];
                }
            }
        }
    }
    if (t < 246){
        #pragma unroll
        for (int m = 0; m < 7; ++m){
            int l = lb + m;
            if (l < Kc) pG[blk * (Kc * Kc) + k * Kc + l] = acc[m];
        }
    }
}

// Reduce partials: G[i] = sum_b pG[b][i]. Coalesced (consecutive i per b).
__global__ __launch_bounds__(256) void k_gred(const float* __restrict__ pG,
                                              float* __restrict__ G){
    int i = blockIdx.x * 256 + threadIdx.x;
    if (i < Kc * Kc){
        float s = 0.f;
        for (int b = 0; b < GBLK; ++b) s += pG[b * (Kc * Kc) + i];
        G[i] = s;
    }
}

// p1[r,c] = fea[r,:]·W[0:64,c] + conv_b[c] ; p2[r,c] = fea[r,:]·W[64:128,c]
__global__ __launch_bounds__(128) void k_p12(const float* __restrict__ fea,
                                             const float* __restrict__ Wl,
                                             const float* __restrict__ bl,
                                             float* __restrict__ p1,
                                             float* __restrict__ p2){
    int bi = blockIdx.x;
    int c  = threadIdx.x;
    const float* fr = fea + bi * Fc;
    float a1 = bl[c], a2 = 0.f;
    #pragma unroll 4
    for (int f = 0; f < Fc; ++f){
        float fv = fr[f];                 // uniform -> scalar load
        a1 += fv * Wl[f * C2 + c];
        a2 += fv * Wl[(Fc + f) * C2 + c];
    }
    p1[bi * C2 + c] = a1;
    p2[bi * C2 + c] = a2;
}

// BN1 stats from closed form (per-r part). 4 r's per block, c = thread.
__global__ __launch_bounds__(128) void k_stats2(const float* __restrict__ ST,
                                                const float* __restrict__ cntf,
                                                const float* __restrict__ Wl,
                                                const float* __restrict__ p1,
                                                const float* __restrict__ p2,
                                                float* __restrict__ sum1,
                                                float* __restrict__ sq1){
    int c  = threadIdx.x;
    int r0 = blockIdx.x * 4;
    float w3[Kc];
    #pragma unroll
    for (int k = 0; k < Kc; ++k) w3[k] = Wl[(C2 + k) * C2 + c];
    float s1 = 0.f, q1 = 0.f;
    for (int rr = 0; rr < 4; ++rr){
        int r = r0 + rr;
        const float* Sr = ST + r * (2 * Kc);         // uniform -> s_loads
        const float* Tr = Sr + Kc;
        float p1v = p1[r * C2 + c], p2v = p2[r * C2 + c];
        float u = 0.f, t = 0.f;
        #pragma unroll
        for (int k = 0; k < Kc; ++k){
            u += Sr[k] * w3[k];
            t += Tr[k] * w3[k];
        }
        float cn = cntf[r];                          // uniform
        s1 += (float)NAt * p1v + cn * p2v + u;
        q1 += (float)NAt * p1v * p1v + cn * p2v * p2v
            + 2.f * cn * p1v * p2v + 2.f * p1v * u + 2.f * p2v * t;
    }
    atomicAdd(&sum1[c], s1);
    atomicAdd(&sq1[c],  q1);
}

// BN1 finalize: add global Gram term q = w3^T G w3 to sq, then affine fold.
__global__ void k_fin1(const float* __restrict__ sum, const float* __restrict__ sq,
                       const float* __restrict__ G,   const float* __restrict__ Wl,
                       const float* __restrict__ g,   const float* __restrict__ b,
                       float* __restrict__ a, float* __restrict__ bb, float invM){
    int c = threadIdx.x;
    float w3[Kc];
    #pragma unroll
    for (int k = 0; k < Kc; ++k) w3[k] = Wl[(C2 + k) * C2 + c];
    float q = 0.f;
    for (int k = 0; k < Kc; ++k){
        const float* Gr = G + k * Kc;                // uniform -> s_loads
        float gw = 0.f;
        #pragma unroll
        for (int l = 0; l < Kc; ++l) gw += Gr[l] * w3[l];
        q += w3[k] * gw;
    }
    float m = sum[c] * invM;
    float v = (sq[c] + q) * invM - m * m;
    float ac = g[c] * rsqrtf(v + EPSBN);
    a[c]  = ac;
    bb[c] = b[c] - m * ac;
}

// BN2 finalize (plain).
__global__ void k_fin(const float* __restrict__ sum, const float* __restrict__ sq,
                      const float* __restrict__ g,   const float* __restrict__ b,
                      float* __restrict__ a, float* __restrict__ bb, float invM){
    int c = threadIdx.x;
    float m = sum[c] * invM;
    float v = sq[c] * invM - m * m;
    float ac = g[c] * rsqrtf(v + EPSBN);
    a[c]  = ac;
    bb[c] = b[c] - m * ac;
}

// Pass 2: EXACT R3 configuration (measured 81.4 us, VGPR 60, occupancy 31%).
// (256,1) in R5 collapsed occupancy -> ~+54 us/launch. Keep (256,2).
__global__ __launch_bounds__(256, 2) void k_apply(const float* __restrict__ nbr,
                                                  const int*   __restrict__ adj,
                                                  const float* __restrict__ Wl,
                                                  const float* __restrict__ p1,
                                                  const float* __restrict__ p2,
                                                  const float* __restrict__ a1,
                                                  const float* __restrict__ bb1,
                                                  float* __restrict__ summed,
                                                  float* __restrict__ sum2,
                                                  float* __restrict__ sq2){
    int bi = blockIdx.x;
    int f  = threadIdx.x & 63;
    int jg = __builtin_amdgcn_readfirstlane(threadIdx.x >> 6);  // SGPR
    __shared__ float red[JG][Fc];

    float wa[Kc], wb[Kc];
    #pragma unroll
    for (int k = 0; k < Kc; ++k){
        wa[k] = Wl[(C2 + k) * C2 + f];
        wb[k] = Wl[(C2 + k) * C2 + Fc + f];
    }
    float pa1 = p1[bi * C2 + f],      pa2 = p2[bi * C2 + f];
    float pb1 = p1[bi * C2 + Fc + f], pb2 = p2[bi * C2 + Fc + f];
    float A1 = a1[f],      B1 = bb1[f];
    float A2 = a1[Fc + f], B2 = bb1[Fc + f];
    const float* nb = nbr + (size_t)bi * (NAt * Kc);
    const int*   aj = adj + bi * NAt;

    float acc = 0.f;
    int j0 = jg * JPW;
    for (int j = j0; j < j0 + JPW; ++j){
        const float* nr = nb + j * Kc;        // wave-uniform -> s_loads
        float ajf = (float)aj[j];
        float f0 = 0.f, f1 = 0.f, c0 = 0.f, c1 = 0.f;
        #pragma unroll
        for (int k = 0; k < 40; k += 2){
            float n0 = nr[k], n1 = nr[k + 1];
            f0 += n0 * wa[k];     f1 += n1 * wa[k + 1];
            c0 += n0 * wb[k];     c1 += n1 * wb[k + 1];
        }
        { float n0 = nr[40]; f0 += n0 * wa[40]; c0 += n0 * wb[40]; }
        float gf = (pa1 + ajf * pa2 + (f0 + f1)) * A1 + B1;
        float gc = (pb1 + ajf * pb2 + (c0 + c1)) * A2 + B2;
        acc += sgm_(gf) * sp_(gc);
    }
    red[jg][f] = acc;
    __syncthreads();
    if (jg == 0){
        acc = red[0][f] + red[1][f] + red[2][f] + red[3][f];
        summed[bi * Fc + f] = acc;
        atomicAdd(&sum2[f], acc);
        atomicAdd(&sq2[f],  acc * acc);
    }
}

// fea = softplus(fea + BN2(summed))
__global__ __launch_bounds__(256) void k_update(float* __restrict__ fea,
                                                const float* __restrict__ summed,
                                                const float* __restrict__ a2,
                                                const float* __restrict__ bb2){
    int idx = blockIdx.x * 256 + threadIdx.x;
    int f   = idx & 63;
    float v = fea[idx] + summed[idx] * a2[f] + bb2[f];
    fea[idx] = sp_(v);
}

// crys = mean_i fea; out = softplus(softplus(crys)@fcW + fcb) @ outW + outb
__global__ __launch_bounds__(128) void k_final(const float* __restrict__ fea,
                                               const float* __restrict__ fcW,
                                               const float* __restrict__ fcb,
                                               const float* __restrict__ outW,
                                               const float* __restrict__ outb,
                                               float* __restrict__ out){
    int b = blockIdx.x;
    int t = threadIdx.x;
    __shared__ float spc[Fc];
    __shared__ float red[Hc];
    if (t < Fc){
        float s = 0.f;
        for (int i = 0; i < NAt; ++i) s += fea[(b * NAt + i) * Fc + t];
        spc[t] = sp_(s * (1.f / NAt));
    }
    __syncthreads();
    float h = fcb[t];
    #pragma unroll 4
    for (int f = 0; f < Fc; ++f) h += spc[f] * fcW[f * Hc + t];
    h = sp_(h);
    red[t] = h * outW[t];
    __syncthreads();
    for (int off = 64; off > 0; off >>= 1){
        if (t < off) red[t] += red[t + off];
        __syncthreads();
    }
    if (t == 0) out[b] = red[0] + outb[0];
}

extern "C" void kernel_launch(void* const* d_in, const int* in_sizes, int n_in,
                              void* d_out, int out_size, void* d_ws, size_t ws_size,
                              hipStream_t stream){
    const float* atom  = (const float*)d_in[0];
    const float* nbr   = (const float*)d_in[1];
    const int*   adj   = (const int*)  d_in[2];
    const float* embW  = (const float*)d_in[3];
    const float* embB  = (const float*)d_in[4];
    const float* convW = (const float*)d_in[5];
    const float* convB = (const float*)d_in[6];
    const float* bn1g  = (const float*)d_in[7];
    const float* bn1b  = (const float*)d_in[8];
    const float* bn2g  = (const float*)d_in[9];
    const float* bn2b  = (const float*)d_in[10];
    const float* fcW   = (const float*)d_in[11];
    const float* fcb   = (const float*)d_in[12];
    const float* outW  = (const float*)d_in[13];
    const float* outb  = (const float*)d_in[14];
    float* out = (float*)d_out;
    float* ws  = (float*)d_ws;

    const int ROWS = N0c * NAt;            // 1536
    float* fea    = ws;                    // 98304 floats
    float* p1     = ws + 98304;            // 196608
    float* p2     = ws + 294912;           // 196608
    float* summed = ws + 491520;           // 98304
    float* S      = ws + 589824;           // stats block (768)
    float* sum1 = S,       *sq1 = S + 128;
    float* sum2 = S + 256, *sq2 = S + 320;
    float* a1   = S + 384, *bb1 = S + 512;
    float* a2   = S + 640, *bb2 = S + 704;
    float* ST   = ws + 590592;             // 1536*82
    float* cntf = ws + 716544;             // 1536
    float* G    = ws + 718080;             // 41*41 = 1681
    // Gram partials REUSE the p1/p2 region (393216 floats >= 192*1681=322752):
    // k_gram/k_gred complete before the layer loop ever writes p1/p2.
    float* pG   = p1;

    k_embed<<<ROWS / 4, 256, 0, stream>>>(atom, embW, embB, fea);
    k_pre  <<<ROWS, 256, 0, stream>>>(nbr, adj, ST, cntf);
    k_gram <<<GBLK, 256, 0, stream>>>(nbr, pG);
    k_gred <<<(Kc * Kc + 255) / 256, 256, 0, stream>>>(pG, G);

    for (int l = 0; l < NCc; ++l){
        const float* Wl = convW + (size_t)l * 169 * C2;
        const float* bl = convB + l * C2;
        hipMemsetAsync(S, 0, 384 * sizeof(float), stream);   // sum1,sq1,sum2,sq2
        k_p12   <<<ROWS, C2, 0, stream>>>(fea, Wl, bl, p1, p2);
        k_stats2<<<ROWS / 4, C2, 0, stream>>>(ST, cntf, Wl, p1, p2, sum1, sq1);
        k_fin1  <<<1, C2, 0, stream>>>(sum1, sq1, G, Wl,
                                       bn1g + l * C2, bn1b + l * C2,
                                       a1, bb1, 1.f / (float)(N0c * NAt * NAt));
        k_apply <<<ROWS, 256, 0, stream>>>(nbr, adj, Wl, p1, p2, a1, bb1,
                                           summed, sum2, sq2);
        k_fin   <<<1, Fc, 0, stream>>>(sum2, sq2, bn2g + l * Fc, bn2b + l * Fc,
                                       a2, bb2, 1.f / (float)(N0c * NAt));
        k_update<<<ROWS * Fc / 256, 256, 0, stream>>>(fea, summed, a2, bb2);
    }

    k_final<<<N0c, Hc, 0, stream>>>(fea, fcW, fcb, outW, outb, out);
}

// Round 7
// 463.163 us; speedup vs baseline: 2.1463x; 1.1706x over previous
//
#include <hip/hip_runtime.h>
#include <math.h>

#define N0c   16
#define NAt   96
#define ORIG  92
#define Fc    64
#define Kc    41
#define Hc    128
#define NCc   3
#define C2    128   // 2F
#define EPSBN 1e-5f
#define JG    4     // j-groups per block
#define JPW   (NAt / JG)   // 24 j's per group
#define GBLK  384   // gram partial blocks
#define RPB   4     // 1536 / 384
#define NRP   44    // nbr row padded to 44 floats (16B-aligned rows)

__device__ __forceinline__ float sp_(float x){
    // stable softplus, fast intrinsics (~1e-6 rel err, threshold is 1e-2)
    return fmaxf(x, 0.f) + __logf(1.f + __expf(-fabsf(x)));
}
__device__ __forceinline__ float sgm_(float x){
    return 1.f / (1.f + __expf(-x));
}

// fea = atom @ emb_W + emb_b   (1536 x 92) @ (92 x 64)
__global__ __launch_bounds__(256) void k_embed(const float* __restrict__ atom,
                                               const float* __restrict__ W,
                                               const float* __restrict__ b,
                                               float* __restrict__ fea){
    int row = blockIdx.x * 4 + (threadIdx.x >> 6);   // wave-uniform row
    int f   = threadIdx.x & 63;
    const float* ar = atom + row * ORIG;
    float acc = b[f];
    #pragma unroll 4
    for (int o = 0; o < ORIG; ++o) acc += ar[o] * W[o * Fc + f];
    fea[row * Fc + f] = acc;
}

// One-time: S_r[k]=sum_j nbr, T_r[k]=sum_j adj*nbr, cnt_r=sum_j adj.
__global__ __launch_bounds__(256) void k_pre(const float* __restrict__ nbr,
                                             const int*   __restrict__ adj,
                                             float* __restrict__ ST,
                                             float* __restrict__ cntf){
    int r    = blockIdx.x;
    int lane = threadIdx.x & 63;
    int jg   = __builtin_amdgcn_readfirstlane(threadIdx.x >> 6);
    __shared__ float rS[JG][Kc], rT[JG][Kc], rc[JG];
    float S = 0.f, T = 0.f, cn = 0.f;
    int j0 = jg * JPW;
    for (int j = j0; j < j0 + JPW; ++j){
        float a = (float)adj[r * NAt + j];           // uniform s_load
        float v = (lane < Kc) ? nbr[((size_t)r * NAt + j) * Kc + lane] : 0.f;
        S += v; T += a * v; cn += a;
    }
    if (lane < Kc){ rS[jg][lane] = S; rT[jg][lane] = T; }
    if (lane == 0) rc[jg] = cn;
    __syncthreads();
    int t = threadIdx.x;
    if (t < Kc){
        ST[r * (2 * Kc) + t]      = rS[0][t] + rS[1][t] + rS[2][t] + rS[3][t];
        ST[r * (2 * Kc) + Kc + t] = rT[0][t] + rT[1][t] + rT[2][t] + rT[3][t];
    }
    if (t == 0) cntf[r] = rc[0] + rc[1] + rc[2] + rc[3];
}

// One-time: per-block PRIVATE partial Gram over RPB r-tiles (no atomics).
__global__ __launch_bounds__(256) void k_gram(const float* __restrict__ nbr,
                                              float* __restrict__ pG){
    int blk = blockIdx.x;
    int t   = threadIdx.x;
    __shared__ float L[NAt * Kc];                    // 15.7 KB
    int k  = t % Kc;
    int lb = (t / Kc) * 7;
    float acc[7] = {0,0,0,0,0,0,0};
    for (int rr = 0; rr < RPB; ++rr){
        int r = blk * RPB + rr;
        __syncthreads();                             // protect L reuse
        for (int idx = t; idx < NAt * Kc; idx += 256)
            L[idx] = nbr[(size_t)r * NAt * Kc + idx];
        __syncthreads();
        if (t < 246){
            #pragma unroll 2
            for (int j = 0; j < NAt; ++j){
                float vk = L[j * Kc + k];
                #pragma unroll
                for (int m = 0; m < 7; ++m){
                    int l = lb + m;
                    if (l < Kc) acc[m] += vk * L[j * Kc + l];
                }
            }
        }
    }
    if (t < 246){
        #pragma unroll
        for (int m = 0; m < 7; ++m){
            int l = lb + m;
            if (l < Kc) pG[blk * (Kc * Kc) + k * Kc + l] = acc[m];
        }
    }
}

// Reduce partials: G[i] = sum_b pG[b][i].
__global__ __launch_bounds__(256) void k_gred(const float* __restrict__ pG,
                                              float* __restrict__ G){
    int i = blockIdx.x * 256 + threadIdx.x;
    if (i < Kc * Kc){
        float s = 0.f;
        for (int b = 0; b < GBLK; ++b) s += pG[b * (Kc * Kc) + i];
        G[i] = s;
    }
}

// One-time: q3[l][c] = w3(l,c)^T G w3(l,c) for all layers/channels.
// G staged in LDS (broadcast reads) — kills the k_fin1 scalar-load chain.
__global__ __launch_bounds__(128) void k_quad(const float* __restrict__ G,
                                              const float* __restrict__ convW,
                                              float* __restrict__ q3){
    int l = blockIdx.x, c = threadIdx.x;
    const float* Wl = convW + (size_t)l * 169 * C2;
    __shared__ float GL[Kc * Kc];                    // 6.7 KB
    for (int i = c; i < Kc * Kc; i += 128) GL[i] = G[i];
    float w3[Kc];
    #pragma unroll
    for (int k = 0; k < Kc; ++k) w3[k] = Wl[(C2 + k) * C2 + c];
    __syncthreads();
    float q = 0.f;
    for (int k = 0; k < Kc; ++k){
        float gw = 0.f;
        #pragma unroll
        for (int m = 0; m < Kc; ++m) gw += GL[k * Kc + m] * w3[m];
        q += w3[k] * gw;
    }
    q3[l * C2 + c] = q;
}

// p1[r,c] = fea[r,:]·W[0:64,c] + conv_b[c] ; p2[r,c] = fea[r,:]·W[64:128,c]
__global__ __launch_bounds__(128) void k_p12(const float* __restrict__ fea,
                                             const float* __restrict__ Wl,
                                             const float* __restrict__ bl,
                                             float* __restrict__ p1,
                                             float* __restrict__ p2){
    int bi = blockIdx.x;
    int c  = threadIdx.x;
    const float* fr = fea + bi * Fc;
    float a1 = bl[c], a2 = 0.f;
    #pragma unroll 4
    for (int f = 0; f < Fc; ++f){
        float fv = fr[f];                 // uniform -> scalar load
        a1 += fv * Wl[f * C2 + c];
        a2 += fv * Wl[(Fc + f) * C2 + c];
    }
    p1[bi * C2 + c] = a1;
    p2[bi * C2 + c] = a2;
}

// BN1 stats from closed form (per-r part). 4 r's per block, c = thread.
__global__ __launch_bounds__(128) void k_stats2(const float* __restrict__ ST,
                                                const float* __restrict__ cntf,
                                                const float* __restrict__ Wl,
                                                const float* __restrict__ p1,
                                                const float* __restrict__ p2,
                                                float* __restrict__ sum1,
                                                float* __restrict__ sq1){
    int c  = threadIdx.x;
    int r0 = blockIdx.x * 4;
    float w3[Kc];
    #pragma unroll
    for (int k = 0; k < Kc; ++k) w3[k] = Wl[(C2 + k) * C2 + c];
    float s1 = 0.f, q1 = 0.f;
    for (int rr = 0; rr < 4; ++rr){
        int r = r0 + rr;
        const float* Sr = ST + r * (2 * Kc);         // uniform -> s_loads
        const float* Tr = Sr + Kc;
        float p1v = p1[r * C2 + c], p2v = p2[r * C2 + c];
        float u = 0.f, t = 0.f;
        #pragma unroll
        for (int k = 0; k < Kc; ++k){
            u += Sr[k] * w3[k];
            t += Tr[k] * w3[k];
        }
        float cn = cntf[r];                          // uniform
        s1 += (float)NAt * p1v + cn * p2v + u;
        q1 += (float)NAt * p1v * p1v + cn * p2v * p2v
            + 2.f * cn * p1v * p2v + 2.f * p1v * u + 2.f * p2v * t;
    }
    atomicAdd(&sum1[c], s1);
    atomicAdd(&sq1[c],  q1);
}

// BN1 finalize: sq += precomputed Gram term q[c], then affine fold.
__global__ void k_fin1(const float* __restrict__ sum, const float* __restrict__ sq,
                       const float* __restrict__ q,
                       const float* __restrict__ g,   const float* __restrict__ b,
                       float* __restrict__ a, float* __restrict__ bb, float invM){
    int c = threadIdx.x;
    float m = sum[c] * invM;
    float v = (sq[c] + q[c]) * invM - m * m;
    float ac = g[c] * rsqrtf(v + EPSBN);
    a[c]  = ac;
    bb[c] = b[c] - m * ac;
}

// BN2 finalize (plain).
__global__ void k_fin(const float* __restrict__ sum, const float* __restrict__ sq,
                      const float* __restrict__ g,   const float* __restrict__ b,
                      float* __restrict__ a, float* __restrict__ bb, float invM){
    int c = threadIdx.x;
    float m = sum[c] * invM;
    float v = sq[c] * invM - m * m;
    float ac = g[c] * rsqrtf(v + EPSBN);
    a[c]  = ac;
    bb[c] = b[c] - m * ac;
}

// Pass 2 v3: nbr tile staged in LDS (rows padded to 44 -> 16B-aligned, so
// the unrolled k-loop can merge into ds_read_b128). Weights in VGPRs.
__global__ __launch_bounds__(256, 2) void k_apply(const float* __restrict__ nbr,
                                                  const int*   __restrict__ adj,
                                                  const float* __restrict__ Wl,
                                                  const float* __restrict__ p1,
                                                  const float* __restrict__ p2,
                                                  const float* __restrict__ a1,
                                                  const float* __restrict__ bb1,
                                                  float* __restrict__ summed,
                                                  float* __restrict__ sum2,
                                                  float* __restrict__ sq2){
    int bi = blockIdx.x;
    int f  = threadIdx.x & 63;
    int jg = __builtin_amdgcn_readfirstlane(threadIdx.x >> 6);  // SGPR
    __shared__ float nrL[NAt * NRP];                 // 16.9 KB
    __shared__ float red[JG][Fc];

    const float* nb = nbr + (size_t)bi * (NAt * Kc);
    #pragma unroll 4
    for (int idx = threadIdx.x; idx < NAt * NRP; idx += 256){
        int row = idx / NRP;
        int col = idx - row * NRP;
        nrL[idx] = (col < Kc) ? nb[row * Kc + col] : 0.f;
    }

    float wa[Kc], wb[Kc];
    #pragma unroll
    for (int k = 0; k < Kc; ++k){
        wa[k] = Wl[(C2 + k) * C2 + f];
        wb[k] = Wl[(C2 + k) * C2 + Fc + f];
    }
    float pa1 = p1[bi * C2 + f],      pa2 = p2[bi * C2 + f];
    float pb1 = p1[bi * C2 + Fc + f], pb2 = p2[bi * C2 + Fc + f];
    float A1 = a1[f],      B1 = bb1[f];
    float A2 = a1[Fc + f], B2 = bb1[Fc + f];
    const int* aj = adj + bi * NAt;
    __syncthreads();

    float acc = 0.f;
    int j0 = jg * JPW;
    for (int j = j0; j < j0 + JPW; ++j){
        const float* nr = &nrL[j * NRP];             // uniform LDS addr -> broadcast
        float ajf = (float)aj[j];
        float f0 = 0.f, f1 = 0.f, c0 = 0.f, c1 = 0.f;
        #pragma unroll
        for (int k = 0; k < 40; k += 2){
            float n0 = nr[k], n1 = nr[k + 1];
            f0 += n0 * wa[k];     f1 += n1 * wa[k + 1];
            c0 += n0 * wb[k];     c1 += n1 * wb[k + 1];
        }
        { float n0 = nr[40]; f0 += n0 * wa[40]; c0 += n0 * wb[40]; }
        float gf = (pa1 + ajf * pa2 + (f0 + f1)) * A1 + B1;
        float gc = (pb1 + ajf * pb2 + (c0 + c1)) * A2 + B2;
        acc += sgm_(gf) * sp_(gc);
    }
    red[jg][f] = acc;
    __syncthreads();
    if (jg == 0){
        acc = red[0][f] + red[1][f] + red[2][f] + red[3][f];
        summed[bi * Fc + f] = acc;
        atomicAdd(&sum2[f], acc);
        atomicAdd(&sq2[f],  acc * acc);
    }
}

// fea = softplus(fea + BN2(summed))
__global__ __launch_bounds__(256) void k_update(float* __restrict__ fea,
                                                const float* __restrict__ summed,
                                                const float* __restrict__ a2,
                                                const float* __restrict__ bb2){
    int idx = blockIdx.x * 256 + threadIdx.x;
    int f   = idx & 63;
    float v = fea[idx] + summed[idx] * a2[f] + bb2[f];
    fea[idx] = sp_(v);
}

// crys = mean_i fea; out = softplus(softplus(crys)@fcW + fcb) @ outW + outb
__global__ __launch_bounds__(128) void k_final(const float* __restrict__ fea,
                                               const float* __restrict__ fcW,
                                               const float* __restrict__ fcb,
                                               const float* __restrict__ outW,
                                               const float* __restrict__ outb,
                                               float* __restrict__ out){
    int b = blockIdx.x;
    int t = threadIdx.x;
    __shared__ float spc[Fc];
    __shared__ float red[Hc];
    if (t < Fc){
        float s = 0.f;
        for (int i = 0; i < NAt; ++i) s += fea[(b * NAt + i) * Fc + t];
        spc[t] = sp_(s * (1.f / NAt));
    }
    __syncthreads();
    float h = fcb[t];
    #pragma unroll 4
    for (int f = 0; f < Fc; ++f) h += spc[f] * fcW[f * Hc + t];
    h = sp_(h);
    red[t] = h * outW[t];
    __syncthreads();
    for (int off = 64; off > 0; off >>= 1){
        if (t < off) red[t] += red[t + off];
        __syncthreads();
    }
    if (t == 0) out[b] = red[0] + outb[0];
}

extern "C" void kernel_launch(void* const* d_in, const int* in_sizes, int n_in,
                              void* d_out, int out_size, void* d_ws, size_t ws_size,
                              hipStream_t stream){
    const float* atom  = (const float*)d_in[0];
    const float* nbr   = (const float*)d_in[1];
    const int*   adj   = (const int*)  d_in[2];
    const float* embW  = (const float*)d_in[3];
    const float* embB  = (const float*)d_in[4];
    const float* convW = (const float*)d_in[5];
    const float* convB = (const float*)d_in[6];
    const float* bn1g  = (const float*)d_in[7];
    const float* bn1b  = (const float*)d_in[8];
    const float* bn2g  = (const float*)d_in[9];
    const float* bn2b  = (const float*)d_in[10];
    const float* fcW   = (const float*)d_in[11];
    const float* fcb   = (const float*)d_in[12];
    const float* outW  = (const float*)d_in[13];
    const float* outb  = (const float*)d_in[14];
    float* out = (float*)d_out;
    float* ws  = (float*)d_ws;

    const int ROWS = N0c * NAt;            // 1536
    // pG (384*1681 = 645504 floats) lives at ws[0] and is DEAD before
    // k_embed writes fea — gram kernels run first on the stream.
    float* pG     = ws;
    float* fea    = ws;                    // 98304 floats (after gram)
    float* p1     = ws + 98304;            // 196608
    float* p2     = ws + 294912;           // 196608
    float* summed = ws + 491520;           // 98304
    float* S      = ws + 589824;           // stats block (768)
    float* sum1 = S,       *sq1 = S + 128;
    float* sum2 = S + 256, *sq2 = S + 320;
    float* a1   = S + 384, *bb1 = S + 512;
    float* a2   = S + 640, *bb2 = S + 704;
    float* ST   = ws + 590592;             // 1536*82 -> ends 716544
    float* cntf = ws + 716544;             // 1536    -> ends 718080
    float* G    = ws + 718080;             // 1681    -> ends 719761
    float* q3   = ws + 719776;             // 3*128   -> ends 720160

    k_gram <<<GBLK, 256, 0, stream>>>(nbr, pG);
    k_gred <<<(Kc * Kc + 255) / 256, 256, 0, stream>>>(pG, G);
    k_quad <<<NCc, C2, 0, stream>>>(G, convW, q3);
    k_embed<<<ROWS / 4, 256, 0, stream>>>(atom, embW, embB, fea);
    k_pre  <<<ROWS, 256, 0, stream>>>(nbr, adj, ST, cntf);

    for (int l = 0; l < NCc; ++l){
        const float* Wl = convW + (size_t)l * 169 * C2;
        const float* bl = convB + l * C2;
        hipMemsetAsync(S, 0, 384 * sizeof(float), stream);   // sum1,sq1,sum2,sq2
        k_p12   <<<ROWS, C2, 0, stream>>>(fea, Wl, bl, p1, p2);
        k_stats2<<<ROWS / 4, C2, 0, stream>>>(ST, cntf, Wl, p1, p2, sum1, sq1);
        k_fin1  <<<1, C2, 0, stream>>>(sum1, sq1, q3 + l * C2,
                                       bn1g + l * C2, bn1b + l * C2,
                                       a1, bb1, 1.f / (float)(N0c * NAt * NAt));
        k_apply <<<ROWS, 256, 0, stream>>>(nbr, adj, Wl, p1, p2, a1, bb1,
                                           summed, sum2, sq2);
        k_fin   <<<1, Fc, 0, stream>>>(sum2, sq2, bn2g + l * Fc, bn2b + l * Fc,
                                       a2, bb2, 1.f / (float)(N0c * NAt));
        k_update<<<ROWS * Fc / 256, 256, 0, stream>>>(fea, summed, a2, bb2);
    }

    k_final<<<N0c, Hc, 0, stream>>>(fea, fcW, fcb, outW, outb, out);
}

// Round 8
// 385.896 us; speedup vs baseline: 2.5760x; 1.2002x over previous
//
#include <hip/hip_runtime.h>
#include <math.h>

#define N0c   16
#define NAt   96
#define ORIG  92
#define Fc    64
#define Kc    41
#define Hc    128
#define NCc   3
#define C2    128   // 2F
#define EPSBN 1e-5f
#define JG    4
#define JPW   (NAt / JG)
#define GBLK  192   // gram blocks (8 r's each, 2 j-phases -> 384 partials)
#define GPART (GBLK * 2)
#define NREP  32    // atomic replica slots
#define INV1  (1.f / (float)(N0c * NAt * NAt))
#define INV2  (1.f / (float)(N0c * NAt))

__device__ __forceinline__ float sp_(float x){
    return fmaxf(x, 0.f) + __logf(1.f + __expf(-fabsf(x)));
}
__device__ __forceinline__ float sgm_(float x){
    return 1.f / (1.f + __expf(-x));
}

// fea = atom @ emb_W + emb_b
__global__ __launch_bounds__(256) void k_embed(const float* __restrict__ atom,
                                               const float* __restrict__ W,
                                               const float* __restrict__ b,
                                               float* __restrict__ fea){
    int row = blockIdx.x * 4 + (threadIdx.x >> 6);
    int f   = threadIdx.x & 63;
    const float* ar = atom + row * ORIG;
    float acc = b[f];
    #pragma unroll 4
    for (int o = 0; o < ORIG; ++o) acc += ar[o] * W[o * Fc + f];
    fea[row * Fc + f] = acc;
}

// One-time: S_r, T_r, cnt_r.
__global__ __launch_bounds__(256) void k_pre(const float* __restrict__ nbr,
                                             const int*   __restrict__ adj,
                                             float* __restrict__ ST,
                                             float* __restrict__ cntf){
    int r    = blockIdx.x;
    int lane = threadIdx.x & 63;
    int jg   = __builtin_amdgcn_readfirstlane(threadIdx.x >> 6);
    __shared__ float rS[JG][Kc], rT[JG][Kc], rc[JG];
    float S = 0.f, T = 0.f, cn = 0.f;
    int j0 = jg * JPW;
    for (int j = j0; j < j0 + JPW; ++j){
        float a = (float)adj[r * NAt + j];
        float v = (lane < Kc) ? nbr[((size_t)r * NAt + j) * Kc + lane] : 0.f;
        S += v; T += a * v; cn += a;
    }
    if (lane < Kc){ rS[jg][lane] = S; rT[jg][lane] = T; }
    if (lane == 0) rc[jg] = cn;
    __syncthreads();
    int t = threadIdx.x;
    if (t < Kc){
        ST[r * (2 * Kc) + t]      = rS[0][t] + rS[1][t] + rS[2][t] + rS[3][t];
        ST[r * (2 * Kc) + Kc + t] = rT[0][t] + rT[1][t] + rT[2][t] + rT[3][t];
    }
    if (t == 0) cntf[r] = rc[0] + rc[1] + rc[2] + rc[3];
}

// One-time Gram partials, 2k x 7l register tile, 2-way j split.
__global__ __launch_bounds__(256) void k_gram(const float* __restrict__ nbr,
                                              float* __restrict__ pG){
    int blk = blockIdx.x;
    int t   = threadIdx.x;
    int jp  = t >> 7;            // j phase 0/1
    int idx = t & 127;           // tile id, active if < 126
    int k   = (idx % 21) * 2;    // k, k+1
    int lb  = (idx / 21) * 7;    // 6 groups x 7 covers 41 (guarded)
    __shared__ float L[NAt * Kc];
    float a0[7] = {0,0,0,0,0,0,0}, a1[7] = {0,0,0,0,0,0,0};
    for (int rr = 0; rr < 8; ++rr){
        int r = blk * 8 + rr;
        __syncthreads();
        for (int i = t; i < NAt * Kc; i += 256)
            L[i] = nbr[(size_t)r * NAt * Kc + i];
        __syncthreads();
        if (idx < 126){
            for (int j = jp; j < NAt; j += 2){
                float vk0 = L[j * Kc + k];
                float vk1 = (k + 1 < Kc) ? L[j * Kc + k + 1] : 0.f;
                #pragma unroll
                for (int m = 0; m < 7; ++m){
                    if (lb + m < Kc){
                        float lv = L[j * Kc + lb + m];
                        a0[m] += vk0 * lv;
                        a1[m] += vk1 * lv;
                    }
                }
            }
        }
    }
    if (idx < 126){
        float* dst = pG + (size_t)(blk * 2 + jp) * (Kc * Kc);
        #pragma unroll
        for (int m = 0; m < 7; ++m){
            if (lb + m < Kc){
                dst[k * Kc + lb + m] = a0[m];
                if (k + 1 < Kc) dst[(k + 1) * Kc + lb + m] = a1[m];
            }
        }
    }
}

__global__ __launch_bounds__(256) void k_gred(const float* __restrict__ pG,
                                              float* __restrict__ G){
    int i = blockIdx.x * 256 + threadIdx.x;
    if (i < Kc * Kc){
        float s = 0.f;
        for (int b = 0; b < GPART; ++b) s += pG[(size_t)b * (Kc * Kc) + i];
        G[i] = s;
    }
}

// One-time: transposed padded W3: W3T[l][c][44] (16B-aligned rows, zero pad)
__global__ void k_wt(const float* __restrict__ convW, float* __restrict__ W3T){
    int l = blockIdx.x, c = threadIdx.x;
    const float* Wl = convW + (size_t)l * 169 * C2;
    float* dst = W3T + ((size_t)l * C2 + c) * 44;
    for (int k = 0; k < Kc; ++k) dst[k] = Wl[(C2 + k) * C2 + c];
    dst[41] = 0.f; dst[42] = 0.f; dst[43] = 0.f;
}

// One-time: q3[l][c] = w3^T G w3
__global__ __launch_bounds__(128) void k_quad(const float* __restrict__ G,
                                              const float* __restrict__ convW,
                                              float* __restrict__ q3){
    int l = blockIdx.x, c = threadIdx.x;
    const float* Wl = convW + (size_t)l * 169 * C2;
    __shared__ float GL[Kc * Kc];
    for (int i = c; i < Kc * Kc; i += 128) GL[i] = G[i];
    float w3[Kc];
    #pragma unroll
    for (int k = 0; k < Kc; ++k) w3[k] = Wl[(C2 + k) * C2 + c];
    __syncthreads();
    float q = 0.f;
    for (int k = 0; k < Kc; ++k){
        float gw = 0.f;
        #pragma unroll
        for (int m = 0; m < Kc; ++m) gw += GL[k * Kc + m] * w3[m];
        q += w3[k] * gw;
    }
    q3[l * C2 + c] = q;
}

// Fused p12 + closed-form BN1 stats. 2 rows per block, c = thread.
__global__ __launch_bounds__(128) void k_front(const float* __restrict__ fea,
                                               const float* __restrict__ Wl,
                                               const float* __restrict__ bl,
                                               const float* __restrict__ W3Tl,
                                               const float* __restrict__ ST,
                                               const float* __restrict__ cntf,
                                               float* __restrict__ p1,
                                               float* __restrict__ p2,
                                               float* __restrict__ sum1R,
                                               float* __restrict__ sq1R){
    int c = threadIdx.x;
    float w3[Kc];
    const float* wt = W3Tl + c * 44;       // per-lane contiguous -> float4 loads
    #pragma unroll
    for (int k = 0; k < 40; k += 4){
        float4 v = *(const float4*)(wt + k);
        w3[k] = v.x; w3[k+1] = v.y; w3[k+2] = v.z; w3[k+3] = v.w;
    }
    w3[40] = wt[40];
    float s1 = 0.f, q1 = 0.f;
    for (int rr = 0; rr < 2; ++rr){
        int r = blockIdx.x * 2 + rr;
        const float* fr = fea + r * Fc;
        float a1 = bl[c], a2 = 0.f;
        #pragma unroll 8
        for (int f = 0; f < Fc; ++f){
            float fv = fr[f];              // uniform -> s_load
            a1 += fv * Wl[f * C2 + c];
            a2 += fv * Wl[(Fc + f) * C2 + c];
        }
        p1[r * C2 + c] = a1;
        p2[r * C2 + c] = a2;
        const float* Sr = ST + r * (2 * Kc);   // uniform -> s_loads
        const float* Tr = Sr + Kc;
        float u = 0.f, tt = 0.f;
        #pragma unroll
        for (int k = 0; k < Kc; ++k){ u += Sr[k] * w3[k]; tt += Tr[k] * w3[k]; }
        float cn = cntf[r];
        s1 += (float)NAt * a1 + cn * a2 + u;
        q1 += (float)NAt * a1 * a1 + cn * a2 * a2
            + 2.f * cn * a1 * a2 + 2.f * a1 * u + 2.f * a2 * tt;
    }
    int slot = blockIdx.x & (NREP - 1);
    atomicAdd(&sum1R[slot * C2 + c], s1);
    atomicAdd(&sq1R[slot * C2 + c], q1);
}

// Pass 2 v4: thread owns one j-row (nr[41] in VGPRs), loops channels;
// weights via wave-uniform s_loads from W3T. BN1-finalize folded into
// prologue. f-range split 2-way across blocks. Sum over j via shfl_xor.
__global__ __launch_bounds__(192, 2) void k_apply(const float* __restrict__ nbr,
                                                  const int*   __restrict__ adj,
                                                  const float* __restrict__ w3t,
                                                  const float* __restrict__ p1,
                                                  const float* __restrict__ p2,
                                                  const float* __restrict__ sum1R,
                                                  const float* __restrict__ sq1R,
                                                  const float* __restrict__ qv,
                                                  const float* __restrict__ g1,
                                                  const float* __restrict__ b1,
                                                  float* __restrict__ summed,
                                                  float* __restrict__ sum2R,
                                                  float* __restrict__ sq2R){
    int tid = threadIdx.x;
    int fh  = blockIdx.x & 1;
    int pr  = blockIdx.x >> 1;
    int f0  = fh * 32;
    int bi0 = pr * 2;
    __shared__ float ABf[4][32];     // A1,B1,A2,B2
    __shared__ float PL[2][4][32];   // pa1,pa2,pb1,pb2 per bi
    __shared__ float Tp[6][32];      // halfgroup partials

    if (tid < 64){                   // fold BN1 finalize (replica reduce)
        int half = tid >> 5, fi = tid & 31;
        int c = half * 64 + f0 + fi;
        float s = 0.f, q = 0.f;
        for (int r = 0; r < NREP; ++r){ s += sum1R[r * C2 + c]; q += sq1R[r * C2 + c]; }
        float m = s * INV1;
        float v = (q + qv[c]) * INV1 - m * m;
        float A = g1[c] * rsqrtf(v + EPSBN);
        ABf[half * 2 + 0][fi] = A;
        ABf[half * 2 + 1][fi] = b1[c] - m * A;
    } else {                         // stage p1/p2 fragments
        int vv = tid - 64;
        #pragma unroll
        for (int h = 0; h < 2; ++h){
            int idx = vv + h * 128;
            int bl_ = idx >> 7, rem = idx & 127, arr = rem >> 5, fi = rem & 31;
            int r = bi0 + bl_;
            int c = ((arr & 2) ? 64 : 0) + f0 + fi;
            const float* src = (arr & 1) ? p2 : p1;
            PL[bl_][arr][fi] = src[r * C2 + c];
        }
    }
    int bi_l = (tid >= 96) ? 1 : 0;
    int j    = tid - bi_l * 96;
    int bi   = bi0 + bi_l;
    float ajf = (float)adj[bi * NAt + j];
    float nr[Kc];
    const float* nrow = nbr + ((size_t)bi * NAt + j) * Kc;
    #pragma unroll
    for (int k = 0; k < Kc; ++k) nr[k] = nrow[k];
    __syncthreads();

    int hg = tid >> 5;
    #pragma unroll 2
    for (int f = 0; f < 32; ++f){
        const float* wA = w3t + (f0 + f) * 44;        // uniform -> s_loads
        const float* wB = w3t + (64 + f0 + f) * 44;
        float d0 = 0.f, d1 = 0.f, e0 = 0.f, e1 = 0.f;
        #pragma unroll
        for (int k = 0; k < 40; k += 2){
            d0 += nr[k] * wA[k];     d1 += nr[k+1] * wA[k+1];
            e0 += nr[k] * wB[k];     e1 += nr[k+1] * wB[k+1];
        }
        d0 += nr[40] * wA[40];
        e0 += nr[40] * wB[40];
        float gf = (PL[bi_l][0][f] + ajf * PL[bi_l][1][f] + (d0 + d1)) * ABf[0][f] + ABf[1][f];
        float gc = (PL[bi_l][2][f] + ajf * PL[bi_l][3][f] + (e0 + e1)) * ABf[2][f] + ABf[3][f];
        float t = sgm_(gf) * sp_(gc);
        t += __shfl_xor(t, 1);  t += __shfl_xor(t, 2);  t += __shfl_xor(t, 4);
        t += __shfl_xor(t, 8);  t += __shfl_xor(t, 16);
        if ((tid & 31) == 0) Tp[hg][f] = t;
    }
    __syncthreads();
    if (tid < 64){
        int bl_ = tid >> 5, fi = tid & 31;
        float s = Tp[bl_ * 3 + 0][fi] + Tp[bl_ * 3 + 1][fi] + Tp[bl_ * 3 + 2][fi];
        summed[(bi0 + bl_) * Fc + f0 + fi] = s;
        int slot = blockIdx.x & (NREP - 1);
        atomicAdd(&sum2R[slot * Fc + f0 + fi], s);
        atomicAdd(&sq2R[slot * Fc + f0 + fi], s * s);
    }
}

// fea = softplus(fea + BN2(summed)), BN2 finalize folded in.
__global__ __launch_bounds__(256) void k_update(float* __restrict__ fea,
                                                const float* __restrict__ summed,
                                                const float* __restrict__ sum2R,
                                                const float* __restrict__ sq2R,
                                                const float* __restrict__ g2,
                                                const float* __restrict__ b2){
    __shared__ float A2L[Fc], B2L[Fc];
    int tid = threadIdx.x;
    if (tid < Fc){
        float s = 0.f, q = 0.f;
        for (int r = 0; r < NREP; ++r){ s += sum2R[r * Fc + tid]; q += sq2R[r * Fc + tid]; }
        float m = s * INV2;
        float v = q * INV2 - m * m;
        float A = g2[tid] * rsqrtf(v + EPSBN);
        A2L[tid] = A;
        B2L[tid] = b2[tid] - m * A;
    }
    __syncthreads();
    int idx = blockIdx.x * 256 + tid;
    int f   = idx & 63;
    fea[idx] = sp_(fea[idx] + summed[idx] * A2L[f] + B2L[f]);
}

// crys = mean_i fea; out = softplus(softplus(crys)@fcW + fcb) @ outW + outb
__global__ __launch_bounds__(128) void k_final(const float* __restrict__ fea,
                                               const float* __restrict__ fcW,
                                               const float* __restrict__ fcb,
                                               const float* __restrict__ outW,
                                               const float* __restrict__ outb,
                                               float* __restrict__ out){
    int b = blockIdx.x;
    int t = threadIdx.x;
    __shared__ float spc[Fc];
    __shared__ float red[Hc];
    if (t < Fc){
        float s = 0.f;
        for (int i = 0; i < NAt; ++i) s += fea[(b * NAt + i) * Fc + t];
        spc[t] = sp_(s * (1.f / NAt));
    }
    __syncthreads();
    float h = fcb[t];
    #pragma unroll 4
    for (int f = 0; f < Fc; ++f) h += spc[f] * fcW[f * Hc + t];
    h = sp_(h);
    red[t] = h * outW[t];
    __syncthreads();
    for (int off = 64; off > 0; off >>= 1){
        if (t < off) red[t] += red[t + off];
        __syncthreads();
    }
    if (t == 0) out[b] = red[0] + outb[0];
}

extern "C" void kernel_launch(void* const* d_in, const int* in_sizes, int n_in,
                              void* d_out, int out_size, void* d_ws, size_t ws_size,
                              hipStream_t stream){
    const float* atom  = (const float*)d_in[0];
    const float* nbr   = (const float*)d_in[1];
    const int*   adj   = (const int*)  d_in[2];
    const float* embW  = (const float*)d_in[3];
    const float* embB  = (const float*)d_in[4];
    const float* convW = (const float*)d_in[5];
    const float* convB = (const float*)d_in[6];
    const float* bn1g  = (const float*)d_in[7];
    const float* bn1b  = (const float*)d_in[8];
    const float* bn2g  = (const float*)d_in[9];
    const float* bn2b  = (const float*)d_in[10];
    const float* fcW   = (const float*)d_in[11];
    const float* fcb   = (const float*)d_in[12];
    const float* outW  = (const float*)d_in[13];
    const float* outb  = (const float*)d_in[14];
    float* out = (float*)d_out;
    float* ws  = (float*)d_ws;

    const int ROWS = N0c * NAt;            // 1536
    float* fea    = ws;                    // 98304
    float* p1     = ws + 98304;            // 196608
    float* p2     = ws + 294912;           // 196608
    float* summed = ws + 491520;           // 98304
    float* SR     = ws + 589824;           // 12288 replica stats
    float* sum1R = SR;          float* sq1R = SR + 4096;
    float* sum2R = SR + 8192;   float* sq2R = SR + 10240;
    float* ST     = ws + 602112;           // 125952
    float* cntf   = ws + 728064;           // 1536
    float* G      = ws + 729600;           // 1681
    float* q3     = ws + 731296;           // 384
    float* W3T    = ws + 731680;           // 3*128*44 = 16896 -> ends 748576
    // pG [0, 384*1681=645504) overlays fea..ST-head; dead after k_gred.
    // Ordering: k_gram -> k_gred happen BEFORE k_embed/k_pre write there.
    float* pG     = ws;

    k_gram <<<GBLK, 256, 0, stream>>>(nbr, pG);
    k_gred <<<(Kc * Kc + 255) / 256, 256, 0, stream>>>(pG, G);
    k_wt   <<<NCc, C2, 0, stream>>>(convW, W3T);
    k_quad <<<NCc, C2, 0, stream>>>(G, convW, q3);
    k_embed<<<ROWS / 4, 256, 0, stream>>>(atom, embW, embB, fea);
    k_pre  <<<ROWS, 256, 0, stream>>>(nbr, adj, ST, cntf);

    for (int l = 0; l < NCc; ++l){
        const float* Wl   = convW + (size_t)l * 169 * C2;
        const float* bl   = convB + l * C2;
        const float* W3Tl = W3T + (size_t)l * C2 * 44;
        hipMemsetAsync(SR, 0, 12288 * sizeof(float), stream);
        k_front <<<ROWS / 2, C2, 0, stream>>>(fea, Wl, bl, W3Tl, ST, cntf,
                                              p1, p2, sum1R, sq1R);
        k_apply <<<ROWS, 192, 0, stream>>>(nbr, adj, W3Tl, p1, p2,
                                           sum1R, sq1R, q3 + l * C2,
                                           bn1g + l * C2, bn1b + l * C2,
                                           summed, sum2R, sq2R);
        k_update<<<ROWS * Fc / 256, 256, 0, stream>>>(fea, summed, sum2R, sq2R,
                                                      bn2g + l * Fc, bn2b + l * Fc);
    }

    k_final<<<N0c, Hc, 0, stream>>>(fea, fcW, fcb, outW, outb, out);
}

// Round 9
// 342.365 us; speedup vs baseline: 2.9035x; 1.1271x over previous
//
#include <hip/hip_runtime.h>
#include <math.h>

#define N0c   16
#define NAt   96
#define ORIG  92
#define Fc    64
#define Kc    41
#define Hc    128
#define NCc   3
#define C2    128   // 2F
#define EPSBN 1e-5f
#define JG    4
#define JPW   (NAt / JG)
#define NREP  32    // atomic replica slots
#define INV1  (1.f / (float)(N0c * NAt * NAt))
#define INV2  (1.f / (float)(N0c * NAt))

__device__ __forceinline__ float sp_(float x){
    return fmaxf(x, 0.f) + __logf(1.f + __expf(-fabsf(x)));
}
__device__ __forceinline__ float sgm_(float x){
    return 1.f / (1.f + __expf(-x));
}

// fea = atom @ emb_W + emb_b
__global__ __launch_bounds__(256) void k_embed(const float* __restrict__ atom,
                                               const float* __restrict__ W,
                                               const float* __restrict__ b,
                                               float* __restrict__ fea){
    int row = blockIdx.x * 4 + (threadIdx.x >> 6);
    int f   = threadIdx.x & 63;
    const float* ar = atom + row * ORIG;
    float acc = b[f];
    #pragma unroll 4
    for (int o = 0; o < ORIG; ++o) acc += ar[o] * W[o * Fc + f];
    fea[row * Fc + f] = acc;
}

// One-time: S_r, T_r, cnt_r.
__global__ __launch_bounds__(256) void k_pre(const float* __restrict__ nbr,
                                             const int*   __restrict__ adj,
                                             float* __restrict__ ST,
                                             float* __restrict__ cntf){
    int r    = blockIdx.x;
    int lane = threadIdx.x & 63;
    int jg   = __builtin_amdgcn_readfirstlane(threadIdx.x >> 6);
    __shared__ float rS[JG][Kc], rT[JG][Kc], rc[JG];
    float S = 0.f, T = 0.f, cn = 0.f;
    int j0 = jg * JPW;
    for (int j = j0; j < j0 + JPW; ++j){
        float a = (float)adj[r * NAt + j];
        float v = (lane < Kc) ? nbr[((size_t)r * NAt + j) * Kc + lane] : 0.f;
        S += v; T += a * v; cn += a;
    }
    if (lane < Kc){ rS[jg][lane] = S; rT[jg][lane] = T; }
    if (lane == 0) rc[jg] = cn;
    __syncthreads();
    int t = threadIdx.x;
    if (t < Kc){
        ST[r * (2 * Kc) + t]      = rS[0][t] + rS[1][t] + rS[2][t] + rS[3][t];
        ST[r * (2 * Kc) + Kc + t] = rT[0][t] + rT[1][t] + rT[2][t] + rT[3][t];
    }
    if (t == 0) cntf[r] = rc[0] + rc[1] + rc[2] + rc[3];
}

// Gram partials v3: rpb r's per block, 128 threads, private partial per block
// (no atomics). Thread owns rows (k,k+1) x 7 l's of the 41x41 output.
__global__ __launch_bounds__(128) void k_gram(const float* __restrict__ nbr,
                                              float* __restrict__ pG, int rpb){
    int blk = blockIdx.x;
    int t   = threadIdx.x;
    int k   = (t % 21) * 2;
    int lb  = (t / 21) * 7;
    __shared__ float L[NAt * Kc];                    // 15.7 KB
    float a0[7] = {0,0,0,0,0,0,0}, a1[7] = {0,0,0,0,0,0,0};
    for (int rr = 0; rr < rpb; ++rr){
        int r = blk * rpb + rr;
        __syncthreads();
        for (int i = t; i < NAt * Kc; i += 128)
            L[i] = nbr[(size_t)r * NAt * Kc + i];
        __syncthreads();
        if (t < 126){
            for (int j = 0; j < NAt; ++j){
                float vk0 = L[j * Kc + k];
                float vk1 = (k + 1 < Kc) ? L[j * Kc + k + 1] : 0.f;
                #pragma unroll
                for (int m = 0; m < 7; ++m){
                    if (lb + m < Kc){
                        float lv = L[j * Kc + lb + m];
                        a0[m] += vk0 * lv;
                        a1[m] += vk1 * lv;
                    }
                }
            }
        }
    }
    if (t < 126){
        float* dst = pG + (size_t)blk * (Kc * Kc);
        #pragma unroll
        for (int m = 0; m < 7; ++m){
            if (lb + m < Kc){
                dst[k * Kc + lb + m] = a0[m];
                if (k + 1 < Kc) dst[(k + 1) * Kc + lb + m] = a1[m];
            }
        }
    }
}

// Phased partial reduce: block (i-chunk, phase) sums 96 partials, one
// atomicAdd per output element (G pre-zeroed). 27*ph blocks of 64.
__global__ __launch_bounds__(64) void k_gred(const float* __restrict__ pG,
                                             float* __restrict__ G){
    int i  = (blockIdx.x % 27) * 64 + threadIdx.x;
    int b0 = (blockIdx.x / 27) * 96;
    if (i < Kc * Kc){
        float s = 0.f;
        #pragma unroll 4
        for (int b = b0; b < b0 + 96; ++b) s += pG[(size_t)b * (Kc * Kc) + i];
        atomicAdd(&G[i], s);
    }
}

// One-time: transposed padded W3: W3T[l][c][44] (16B-aligned rows, zero pad)
__global__ void k_wt(const float* __restrict__ convW, float* __restrict__ W3T){
    int l = blockIdx.x, c = threadIdx.x;
    const float* Wl = convW + (size_t)l * 169 * C2;
    float* dst = W3T + ((size_t)l * C2 + c) * 44;
    for (int k = 0; k < Kc; ++k) dst[k] = Wl[(C2 + k) * C2 + c];
    dst[41] = 0.f; dst[42] = 0.f; dst[43] = 0.f;
}

// One-time: q3[l][c] = w3^T G w3
__global__ __launch_bounds__(128) void k_quad(const float* __restrict__ G,
                                              const float* __restrict__ convW,
                                              float* __restrict__ q3){
    int l = blockIdx.x, c = threadIdx.x;
    const float* Wl = convW + (size_t)l * 169 * C2;
    __shared__ float GL[Kc * Kc];
    for (int i = c; i < Kc * Kc; i += 128) GL[i] = G[i];
    float w3[Kc];
    #pragma unroll
    for (int k = 0; k < Kc; ++k) w3[k] = Wl[(C2 + k) * C2 + c];
    __syncthreads();
    float q = 0.f;
    for (int k = 0; k < Kc; ++k){
        float gw = 0.f;
        #pragma unroll
        for (int m = 0; m < Kc; ++m) gw += GL[k * Kc + m] * w3[m];
        q += w3[k] * gw;
    }
    q3[l * C2 + c] = q;
}

// Fused p12 + closed-form BN1 stats. 2 rows per block, c = thread.
__global__ __launch_bounds__(128) void k_front(const float* __restrict__ fea,
                                               const float* __restrict__ Wl,
                                               const float* __restrict__ bl,
                                               const float* __restrict__ W3Tl,
                                               const float* __restrict__ ST,
                                               const float* __restrict__ cntf,
                                               float* __restrict__ p1,
                                               float* __restrict__ p2,
                                               float* __restrict__ sum1R,
                                               float* __restrict__ sq1R){
    int c = threadIdx.x;
    float w3[Kc];
    const float* wt = W3Tl + c * 44;       // per-lane contiguous -> float4 loads
    #pragma unroll
    for (int k = 0; k < 40; k += 4){
        float4 v = *(const float4*)(wt + k);
        w3[k] = v.x; w3[k+1] = v.y; w3[k+2] = v.z; w3[k+3] = v.w;
    }
    w3[40] = wt[40];
    float s1 = 0.f, q1 = 0.f;
    for (int rr = 0; rr < 2; ++rr){
        int r = blockIdx.x * 2 + rr;
        const float* fr = fea + r * Fc;
        float a1 = bl[c], a2 = 0.f;
        #pragma unroll 8
        for (int f = 0; f < Fc; ++f){
            float fv = fr[f];              // uniform -> s_load
            a1 += fv * Wl[f * C2 + c];
            a2 += fv * Wl[(Fc + f) * C2 + c];
        }
        p1[r * C2 + c] = a1;
        p2[r * C2 + c] = a2;
        const float* Sr = ST + r * (2 * Kc);   // uniform -> s_loads
        const float* Tr = Sr + Kc;
        float u = 0.f, tt = 0.f;
        #pragma unroll
        for (int k = 0; k < Kc; ++k){ u += Sr[k] * w3[k]; tt += Tr[k] * w3[k]; }
        float cn = cntf[r];
        s1 += (float)NAt * a1 + cn * a2 + u;
        q1 += (float)NAt * a1 * a1 + cn * a2 * a2
            + 2.f * cn * a1 * a2 + 2.f * a1 * u + 2.f * a2 * tt;
    }
    int slot = blockIdx.x & (NREP - 1);
    atomicAdd(&sum1R[slot * C2 + c], s1);
    atomicAdd(&sq1R[slot * C2 + c], q1);
}

// Pass 2 v4 (unchanged from R8): thread owns one j-row (nr[41] in VGPRs),
// loops channels; weights via wave-uniform s_loads from W3T.
__global__ __launch_bounds__(192, 2) void k_apply(const float* __restrict__ nbr,
                                                  const int*   __restrict__ adj,
                                                  const float* __restrict__ w3t,
                                                  const float* __restrict__ p1,
                                                  const float* __restrict__ p2,
                                                  const float* __restrict__ sum1R,
                                                  const float* __restrict__ sq1R,
                                                  const float* __restrict__ qv,
                                                  const float* __restrict__ g1,
                                                  const float* __restrict__ b1,
                                                  float* __restrict__ summed,
                                                  float* __restrict__ sum2R,
                                                  float* __restrict__ sq2R){
    int tid = threadIdx.x;
    int fh  = blockIdx.x & 1;
    int pr  = blockIdx.x >> 1;
    int f0  = fh * 32;
    int bi0 = pr * 2;
    __shared__ float ABf[4][32];     // A1,B1,A2,B2
    __shared__ float PL[2][4][32];   // pa1,pa2,pb1,pb2 per bi
    __shared__ float Tp[6][32];      // halfgroup partials

    if (tid < 64){                   // fold BN1 finalize (replica reduce)
        int half = tid >> 5, fi = tid & 31;
        int c = half * 64 + f0 + fi;
        float s = 0.f, q = 0.f;
        for (int r = 0; r < NREP; ++r){ s += sum1R[r * C2 + c]; q += sq1R[r * C2 + c]; }
        float m = s * INV1;
        float v = (q + qv[c]) * INV1 - m * m;
        float A = g1[c] * rsqrtf(v + EPSBN);
        ABf[half * 2 + 0][fi] = A;
        ABf[half * 2 + 1][fi] = b1[c] - m * A;
    } else {                         // stage p1/p2 fragments
        int vv = tid - 64;
        #pragma unroll
        for (int h = 0; h < 2; ++h){
            int idx = vv + h * 128;
            int bl_ = idx >> 7, rem = idx & 127, arr = rem >> 5, fi = rem & 31;
            int r = bi0 + bl_;
            int c = ((arr & 2) ? 64 : 0) + f0 + fi;
            const float* src = (arr & 1) ? p2 : p1;
            PL[bl_][arr][fi] = src[r * C2 + c];
        }
    }
    int bi_l = (tid >= 96) ? 1 : 0;
    int j    = tid - bi_l * 96;
    int bi   = bi0 + bi_l;
    float ajf = (float)adj[bi * NAt + j];
    float nr[Kc];
    const float* nrow = nbr + ((size_t)bi * NAt + j) * Kc;
    #pragma unroll
    for (int k = 0; k < Kc; ++k) nr[k] = nrow[k];
    __syncthreads();

    int hg = tid >> 5;
    #pragma unroll 2
    for (int f = 0; f < 32; ++f){
        const float* wA = w3t + (f0 + f) * 44;        // uniform -> s_loads
        const float* wB = w3t + (64 + f0 + f) * 44;
        float d0 = 0.f, d1 = 0.f, e0 = 0.f, e1 = 0.f;
        #pragma unroll
        for (int k = 0; k < 40; k += 2){
            d0 += nr[k] * wA[k];     d1 += nr[k+1] * wA[k+1];
            e0 += nr[k] * wB[k];     e1 += nr[k+1] * wB[k+1];
        }
        d0 += nr[40] * wA[40];
        e0 += nr[40] * wB[40];
        float gf = (PL[bi_l][0][f] + ajf * PL[bi_l][1][f] + (d0 + d1)) * ABf[0][f] + ABf[1][f];
        float gc = (PL[bi_l][2][f] + ajf * PL[bi_l][3][f] + (e0 + e1)) * ABf[2][f] + ABf[3][f];
        float t = sgm_(gf) * sp_(gc);
        t += __shfl_xor(t, 1);  t += __shfl_xor(t, 2);  t += __shfl_xor(t, 4);
        t += __shfl_xor(t, 8);  t += __shfl_xor(t, 16);
        if ((tid & 31) == 0) Tp[hg][f] = t;
    }
    __syncthreads();
    if (tid < 64){
        int bl_ = tid >> 5, fi = tid & 31;
        float s = Tp[bl_ * 3 + 0][fi] + Tp[bl_ * 3 + 1][fi] + Tp[bl_ * 3 + 2][fi];
        summed[(bi0 + bl_) * Fc + f0 + fi] = s;
        int slot = blockIdx.x & (NREP - 1);
        atomicAdd(&sum2R[slot * Fc + f0 + fi], s);
        atomicAdd(&sq2R[slot * Fc + f0 + fi], s * s);
    }
}

// fea = softplus(fea + BN2(summed)), BN2 finalize folded in.
__global__ __launch_bounds__(256) void k_update(float* __restrict__ fea,
                                                const float* __restrict__ summed,
                                                const float* __restrict__ sum2R,
                                                const float* __restrict__ sq2R,
                                                const float* __restrict__ g2,
                                                const float* __restrict__ b2){
    __shared__ float A2L[Fc], B2L[Fc];
    int tid = threadIdx.x;
    if (tid < Fc){
        float s = 0.f, q = 0.f;
        for (int r = 0; r < NREP; ++r){ s += sum2R[r * Fc + tid]; q += sq2R[r * Fc + tid]; }
        float m = s * INV2;
        float v = q * INV2 - m * m;
        float A = g2[tid] * rsqrtf(v + EPSBN);
        A2L[tid] = A;
        B2L[tid] = b2[tid] - m * A;
    }
    __syncthreads();
    int idx = blockIdx.x * 256 + tid;
    int f   = idx & 63;
    fea[idx] = sp_(fea[idx] + summed[idx] * A2L[f] + B2L[f]);
}

// crys = mean_i fea; out = softplus(softplus(crys)@fcW + fcb) @ outW + outb
__global__ __launch_bounds__(128) void k_final(const float* __restrict__ fea,
                                               const float* __restrict__ fcW,
                                               const float* __restrict__ fcb,
                                               const float* __restrict__ outW,
                                               const float* __restrict__ outb,
                                               float* __restrict__ out){
    int b = blockIdx.x;
    int t = threadIdx.x;
    __shared__ float spc[Fc];
    __shared__ float red[Hc];
    if (t < Fc){
        float s = 0.f;
        for (int i = 0; i < NAt; ++i) s += fea[(b * NAt + i) * Fc + t];
        spc[t] = sp_(s * (1.f / NAt));
    }
    __syncthreads();
    float h = fcb[t];
    #pragma unroll 4
    for (int f = 0; f < Fc; ++f) h += spc[f] * fcW[f * Hc + t];
    h = sp_(h);
    red[t] = h * outW[t];
    __syncthreads();
    for (int off = 64; off > 0; off >>= 1){
        if (t < off) red[t] += red[t + off];
        __syncthreads();
    }
    if (t == 0) out[b] = red[0] + outb[0];
}

extern "C" void kernel_launch(void* const* d_in, const int* in_sizes, int n_in,
                              void* d_out, int out_size, void* d_ws, size_t ws_size,
                              hipStream_t stream){
    const float* atom  = (const float*)d_in[0];
    const float* nbr   = (const float*)d_in[1];
    const int*   adj   = (const int*)  d_in[2];
    const float* embW  = (const float*)d_in[3];
    const float* embB  = (const float*)d_in[4];
    const float* convW = (const float*)d_in[5];
    const float* convB = (const float*)d_in[6];
    const float* bn1g  = (const float*)d_in[7];
    const float* bn1b  = (const float*)d_in[8];
    const float* bn2g  = (const float*)d_in[9];
    const float* bn2b  = (const float*)d_in[10];
    const float* fcW   = (const float*)d_in[11];
    const float* fcb   = (const float*)d_in[12];
    const float* outW  = (const float*)d_in[13];
    const float* outb  = (const float*)d_in[14];
    float* out = (float*)d_out;
    float* ws  = (float*)d_ws;

    const int ROWS = N0c * NAt;            // 1536
    // Persistent layout (floats):
    float* fea    = ws;                    // 98304
    float* p1     = ws + 98304;            // 196608
    float* p2     = ws + 294912;           // 196608
    float* summed = ws + 491520;           // 98304
    float* SR     = ws + 589824;           // 12288 replica stats
    float* sum1R = SR;          float* sq1R = SR + 4096;
    float* sum2R = SR + 8192;   float* sq2R = SR + 10240;
    float* ST     = ws + 602112;           // 125952
    float* cntf   = ws + 728064;           // 1536
    float* q3     = ws + 729600;           // 384
    float* W3T    = ws + 729984;           // 16896 -> PERS end 746880
    const size_t PERS = 746880;

    // Gram scratch: tier the partial count on ws_size (constant per session,
    // so the launch sequence is identical every call — graph-safe).
    size_t ws_f = ws_size / sizeof(float);
    int nblk; float *pG, *G;
    if (ws_f >= PERS + (size_t)1536 * 1681 + 1681 + 64){
        nblk = 1536; pG = ws + PERS; G = pG + (size_t)nblk * 1681;
    } else if (ws_f >= PERS + (size_t)768 * 1681 + 1681 + 64){
        nblk = 768;  pG = ws + PERS; G = pG + (size_t)nblk * 1681;
    } else if (ws_f >= PERS + (size_t)384 * 1681 + 1681 + 64){
        nblk = 384;  pG = ws + PERS; G = pG + (size_t)nblk * 1681;
    } else {
        // compact overlay (proven R8 footprint): pG over fea..summed region
        // (dead until k_embed), G inside ST region (written later by k_pre).
        nblk = 384;  pG = ws;        G = ws + 650000;
    }
    int rpb = 1536 / nblk;
    int ph  = nblk / 96;

    hipMemsetAsync(G, 0, Kc * Kc * sizeof(float), stream);
    k_gram <<<nblk, 128, 0, stream>>>(nbr, pG, rpb);
    k_gred <<<27 * ph, 64, 0, stream>>>(pG, G);
    k_wt   <<<NCc, C2, 0, stream>>>(convW, W3T);
    k_quad <<<NCc, C2, 0, stream>>>(G, convW, q3);
    k_embed<<<ROWS / 4, 256, 0, stream>>>(atom, embW, embB, fea);
    k_pre  <<<ROWS, 256, 0, stream>>>(nbr, adj, ST, cntf);

    for (int l = 0; l < NCc; ++l){
        const float* Wl   = convW + (size_t)l * 169 * C2;
        const float* bl   = convB + l * C2;
        const float* W3Tl = W3T + (size_t)l * C2 * 44;
        hipMemsetAsync(SR, 0, 12288 * sizeof(float), stream);
        k_front <<<ROWS / 2, C2, 0, stream>>>(fea, Wl, bl, W3Tl, ST, cntf,
                                              p1, p2, sum1R, sq1R);
        k_apply <<<ROWS, 192, 0, stream>>>(nbr, adj, W3Tl, p1, p2,
                                           sum1R, sq1R, q3 + l * C2,
                                           bn1g + l * C2, bn1b + l * C2,
                                           summed, sum2R, sq2R);
        k_update<<<ROWS * Fc / 256, 256, 0, stream>>>(fea, summed, sum2R, sq2R,
                                                      bn2g + l * Fc, bn2b + l * Fc);
    }

    k_final<<<N0c, Hc, 0, stream>>>(fea, fcW, fcb, outW, outb, out);
}